// Round 4
// baseline (1101.844 us; speedup 1.0000x reference)
//
#include <hip/hip_runtime.h>

#define NUSERS  200000
#define NMOVIES 200000
#define NROWSF1 (NUSERS + NMOVIES)

// ---------------------------------------------------------------------------
// Stream 1: me edges (RGCN agg). S_e[d] += entity_x[s] -> out_movie[d][0..63]
// Working set: entity_x (102 MB) + S_e half-rows (51 MB) -> L3-resident RMW.
// ---------------------------------------------------------------------------
__global__ __launch_bounds__(256) void edge_me_kernel(
    const int* __restrict__ me,
    const float* __restrict__ entity_x,
    float* __restrict__ out_movie,
    float* __restrict__ cnt_e,
    int E)
{
    const int lane = threadIdx.x & 63;
    int w = (blockIdx.x * blockDim.x + threadIdx.x) >> 6;
    const int nw = (gridDim.x * blockDim.x) >> 6;
    for (int e = w; e < E; e += nw) {
        const int eu = __builtin_amdgcn_readfirstlane(e);
        const int s = me[eu];
        const int d = me[E + eu];
        if (d < NMOVIES) {
            atomicAdd(&out_movie[(size_t)d * 128 + lane],
                      entity_x[(size_t)s * 64 + lane]);
            if (lane == 0) atomicAdd(&cnt_e[d], 1.0f);
        }
    }
}

// ---------------------------------------------------------------------------
// Stream 2: um edges, movie side. S1m[b] += movie_x[a] -> out_movie[b][64..]
// Working set: movie_x (51 MB) + S1m half-rows (51 MB).
// ---------------------------------------------------------------------------
__global__ __launch_bounds__(256) void edge_um_movie_kernel(
    const int* __restrict__ um,
    const float* __restrict__ movie_x,
    float* __restrict__ out_movie,
    float* __restrict__ cntm,
    int E)
{
    const int lane = threadIdx.x & 63;
    int w = (blockIdx.x * blockDim.x + threadIdx.x) >> 6;
    const int nw = (gridDim.x * blockDim.x) >> 6;
    for (int e = w; e < E; e += nw) {
        const int eu = __builtin_amdgcn_readfirstlane(e);
        const int a = um[eu];
        const int b = um[E + eu];
        atomicAdd(&out_movie[(size_t)b * 128 + 64 + lane],
                  movie_x[(size_t)a * 64 + lane]);
        if (lane == 0) atomicAdd(&cntm[b], 1.0f);
    }
}

// ---------------------------------------------------------------------------
// Stream 3: um edges, user side (reversed). S1u[a] += user_x[b]
// Working set: user_x (51 MB) + S1u half-rows (51 MB).
// ---------------------------------------------------------------------------
__global__ __launch_bounds__(256) void edge_um_user_kernel(
    const int* __restrict__ um,
    const float* __restrict__ user_x,
    float* __restrict__ out_user,
    float* __restrict__ cntu,
    int E)
{
    const int lane = threadIdx.x & 63;
    int w = (blockIdx.x * blockDim.x + threadIdx.x) >> 6;
    const int nw = (gridDim.x * blockDim.x) >> 6;
    for (int e = w; e < E; e += nw) {
        const int eu = __builtin_amdgcn_readfirstlane(e);
        const int a = um[eu];
        const int b = um[E + eu];
        atomicAdd(&out_user[(size_t)a * 128 + 64 + lane],
                  user_x[(size_t)b * 64 + lane]);
        if (lane == 0) atomicAdd(&cntu[a], 1.0f);
    }
}

// ---------------------------------------------------------------------------
// Finalize A (movies only): RGCN part.
// Reads S_e from out_movie[m][0..63], overwrites it with
//   r = (S_e@Wrel)/max(ce,1) + Ex@Wroot + brgcn
// ---------------------------------------------------------------------------
__global__ __launch_bounds__(256, 2) void finalize_rgcn_kernel(
    const float* __restrict__ entity_x,
    const float* __restrict__ cnt_e,
    const float* __restrict__ Wrel, const float* __restrict__ Wroot,
    const float* __restrict__ brgcn,
    float* __restrict__ out_movie)
{
    __shared__ float srow[4][128];
    __shared__ float brs[64];
    const int lane = threadIdx.x & 63;
    const int wslot = threadIdx.x >> 6;
    if (threadIdx.x < 64) brs[threadIdx.x] = brgcn[threadIdx.x];
    __syncthreads();

    float Wcr[64], Wco[64];
#pragma unroll
    for (int k = 0; k < 64; ++k) {
        Wcr[k] = Wrel[k * 64 + lane];
        Wco[k] = Wroot[k * 64 + lane];
    }
    const float bv = brs[lane];

    const int gw = (blockIdx.x * blockDim.x + threadIdx.x) >> 6;
    const int nw = (gridDim.x * blockDim.x) >> 6;

    int m = gw;
    if (m >= NMOVIES) return;

    float sev = out_movie[(size_t)m * 128 + lane];
    float exv = entity_x[(size_t)m * 64 + lane];
    float ce  = cnt_e[m];

    while (m < NMOVIES) {
        srow[wslot][lane]      = sev;
        srow[wslot][64 + lane] = exv;

        const int mn = m + nw;
        float sevn = 0.f, exvn = 0.f, cen = 0.f;
        if (mn < NMOVIES) {
            sevn = out_movie[(size_t)mn * 128 + lane];
            exvn = entity_x[(size_t)mn * 64 + lane];
            cen  = cnt_e[mn];
        }

        const float* sep = &srow[wslot][0];
        const float* exp_ = &srow[wslot][64];
        float a3a = 0.f, a3b = 0.f, a4a = 0.f, a4b = 0.f;
#pragma unroll
        for (int k = 0; k < 64; k += 4) {
            const float4 sv = *(const float4*)&sep[k];
            const float4 ev = *(const float4*)&exp_[k];
            a3a = fmaf(sv.x, Wcr[k],     a3a);
            a3b = fmaf(sv.y, Wcr[k + 1], a3b);
            a3a = fmaf(sv.z, Wcr[k + 2], a3a);
            a3b = fmaf(sv.w, Wcr[k + 3], a3b);
            a4a = fmaf(ev.x, Wco[k],     a4a);
            a4b = fmaf(ev.y, Wco[k + 1], a4b);
            a4a = fmaf(ev.z, Wco[k + 2], a4a);
            a4b = fmaf(ev.w, Wco[k + 3], a4b);
        }

        const float inv_ce = 1.0f / fmaxf(ce, 1.0f);
        out_movie[(size_t)m * 128 + lane] =
            (a3a + a3b) * inv_ce + a4a + a4b + bv;

        m = mn;
        sev = sevn; exv = exvn; ce = cen;
    }
}

// ---------------------------------------------------------------------------
// Finalize B (all 400k rows): NGCF transform + x-copy + rgcn add.
// out[r][64..127] = S1@W1 + (x ⊙ S1)@W2 + cnt*(b1+b2) + rgcn_part
// out[r][0..63]   = x[r]
// ---------------------------------------------------------------------------
__global__ __launch_bounds__(256, 2) void finalize_ngcf_kernel(
    const float* __restrict__ user_x,
    const float* __restrict__ movie_x,
    const float* __restrict__ cntu,
    const float* __restrict__ cntm,
    const float* __restrict__ W1, const float* __restrict__ b1,
    const float* __restrict__ W2, const float* __restrict__ b2,
    float* __restrict__ out_user, float* __restrict__ out_movie)
{
    __shared__ float srow[4][128];
    __shared__ float biass[64];
    const int lane = threadIdx.x & 63;
    const int wslot = threadIdx.x >> 6;
    if (threadIdx.x < 64) biass[threadIdx.x] = b1[threadIdx.x] + b2[threadIdx.x];
    __syncthreads();

    float Wc1[64], Wc2[64];
#pragma unroll
    for (int k = 0; k < 64; ++k) {
        Wc1[k] = W1[k * 64 + lane];
        Wc2[k] = W2[k * 64 + lane];
    }
    const float bv = biass[lane];

    const int gw = (blockIdx.x * blockDim.x + threadIdx.x) >> 6;
    const int nw = (gridDim.x * blockDim.x) >> 6;

    int r = gw;
    if (r >= NROWSF1) return;

    float s1v, xv, cnt, rp;
    {
        const bool isU = r < NUSERS;
        const int row = isU ? r : r - NUSERS;
        float* outp = (isU ? out_user : out_movie) + (size_t)row * 128;
        s1v = outp[64 + lane];
        rp  = outp[lane];
        xv  = ((isU ? user_x : movie_x) + (size_t)row * 64)[lane];
        cnt = (isU ? cntu : cntm)[row];
    }

    while (r < NROWSF1) {
        srow[wslot][lane]      = s1v;
        srow[wslot][64 + lane] = xv;

        const int rn = r + nw;
        float s1n = 0.f, xvn = 0.f, cntn = 0.f, rpn = 0.f;
        if (rn < NROWSF1) {
            const bool isU = rn < NUSERS;
            const int row = isU ? rn : rn - NUSERS;
            float* outp = (isU ? out_user : out_movie) + (size_t)row * 128;
            s1n = outp[64 + lane];
            rpn = outp[lane];
            xvn = ((isU ? user_x : movie_x) + (size_t)row * 64)[lane];
            cntn = (isU ? cntu : cntm)[row];
        }

        const float* s1p = &srow[wslot][0];
        const float* xp  = &srow[wslot][64];
        float a1a = 0.f, a1b = 0.f, a2a = 0.f, a2b = 0.f;
#pragma unroll
        for (int k = 0; k < 64; k += 4) {
            const float4 s1q = *(const float4*)&s1p[k];
            const float4 xq  = *(const float4*)&xp[k];
            a1a = fmaf(s1q.x, Wc1[k],     a1a);
            a1b = fmaf(s1q.y, Wc1[k + 1], a1b);
            a1a = fmaf(s1q.z, Wc1[k + 2], a1a);
            a1b = fmaf(s1q.w, Wc1[k + 3], a1b);
            a2a = fmaf(xq.x * s1q.x, Wc2[k],     a2a);
            a2b = fmaf(xq.y * s1q.y, Wc2[k + 1], a2b);
            a2a = fmaf(xq.z * s1q.z, Wc2[k + 2], a2a);
            a2b = fmaf(xq.w * s1q.w, Wc2[k + 3], a2b);
        }

        {
            const bool isU = r < NUSERS;
            const int row = isU ? r : r - NUSERS;
            float* outp = (isU ? out_user : out_movie) + (size_t)row * 128;
            outp[lane] = xv;
            outp[64 + lane] = a1a + a1b + a2a + a2b + cnt * bv + rp;
        }
        r = rn;
        s1v = s1n; xv = xvn; cnt = cntn; rp = rpn;
    }
}

extern "C" void kernel_launch(void* const* d_in, const int* in_sizes, int n_in,
                              void* d_out, int out_size, void* d_ws, size_t ws_size,
                              hipStream_t stream)
{
    const float* user_x   = (const float*)d_in[0];
    const float* movie_x  = (const float*)d_in[1];
    const float* entity_x = (const float*)d_in[2];
    const int*   um       = (const int*)d_in[3];
    const int*   me       = (const int*)d_in[4];
    const float* W1       = (const float*)d_in[5];
    const float* b1       = (const float*)d_in[6];
    const float* W2       = (const float*)d_in[7];
    const float* b2       = (const float*)d_in[8];
    const float* Wrel     = (const float*)d_in[9];
    const float* Wroot    = (const float*)d_in[10];
    const float* brgcn    = (const float*)d_in[11];

    const int E_um = in_sizes[3] / 2;
    const int E_me = in_sizes[4] / 2;

    float* out_user  = (float*)d_out;                         // [NUSERS, 128]
    float* out_movie = out_user + (size_t)NUSERS * 128;       // [NMOVIES, 128]

    // Workspace (floats): cntm, cntu, cnt_e.
    float* cntm  = (float*)d_ws;
    float* cntu  = cntm + NMOVIES;
    float* cnt_e = cntu + NUSERS;
    const size_t ws_used = ((size_t)NMOVIES + NUSERS + NMOVIES) * sizeof(float);

    // Zero accumulators (d_out doubles as S1 / S_e accumulator space).
    hipMemsetAsync(d_out, 0, (size_t)out_size * sizeof(float), stream);
    hipMemsetAsync(d_ws, 0, ws_used, stream);

    // Stream-sequential edge phases, each with an L3-fitting working set.
    edge_me_kernel<<<2048, 256, 0, stream>>>(me, entity_x, out_movie, cnt_e, E_me);
    edge_um_movie_kernel<<<2048, 256, 0, stream>>>(um, movie_x, out_movie, cntm, E_um);
    edge_um_user_kernel<<<2048, 256, 0, stream>>>(um, user_x, out_user, cntu, E_um);

    finalize_rgcn_kernel<<<2048, 256, 0, stream>>>(entity_x, cnt_e,
                                                   Wrel, Wroot, brgcn, out_movie);
    finalize_ngcf_kernel<<<4096, 256, 0, stream>>>(user_x, movie_x, cntu, cntm,
                                                   W1, b1, W2, b2,
                                                   out_user, out_movie);
}

// Round 5
// 707.409 us; speedup vs baseline: 1.5576x; 1.5576x over previous
//
#include <hip/hip_runtime.h>

#define NUSERS  200000
#define NMOVIES 200000
#define NROWS   200000          // all three dst spaces are 200k rows
#define NROWSF1 (NUSERS + NMOVIES)
#define NBLK    ((NROWS + 255) / 256)   // 782 scan blocks per array

// ---------------------------------------------------------------------------
// K1: histogram + within-bucket slot. Thread per edge.
//  arr0: um user-side  (dst = a), arr1: um movie-side (dst = b),
//  arr2: me entity-agg (dst = d).
// ---------------------------------------------------------------------------
__global__ __launch_bounds__(256) void hist_kernel(
    const int* __restrict__ um, const int* __restrict__ me,
    int* __restrict__ cnt_u, int* __restrict__ cnt_m, int* __restrict__ cnt_e,
    int* __restrict__ w_umu, int* __restrict__ w_umm, int* __restrict__ w_me,
    int E_um, int E_me)
{
    const int total = E_um + E_me;
    for (int t = blockIdx.x * blockDim.x + threadIdx.x; t < total;
         t += gridDim.x * blockDim.x) {
        if (t < E_um) {
            const int a = um[t];
            const int b = um[E_um + t];
            w_umu[t] = atomicAdd(&cnt_u[a], 1);
            w_umm[t] = atomicAdd(&cnt_m[b], 1);
        } else {
            const int e = t - E_um;
            const int d = me[E_me + e];
            w_me[e] = atomicAdd(&cnt_e[d], 1);
        }
    }
}

// ---------------------------------------------------------------------------
// K2a: block-local exclusive scan of the 3 cnt arrays (256/block).
// Writes sl (block-local exclusive prefix) and per-block sums.
// ---------------------------------------------------------------------------
__global__ __launch_bounds__(256) void scan_blocks_kernel(
    const int* __restrict__ cnt_all,   // [3][NROWS]
    int* __restrict__ sl_all,          // [3][NROWS]
    int* __restrict__ bsum)            // [3][NBLK]
{
    __shared__ int tmp[256];
    const int tid = threadIdx.x;
    const int arr = blockIdx.x / NBLK;
    const int blk = blockIdx.x % NBLK;
    const int idx = blk * 256 + tid;
    const int val = (idx < NROWS) ? cnt_all[arr * NROWS + idx] : 0;
    tmp[tid] = val;
    __syncthreads();
#pragma unroll
    for (int off = 1; off < 256; off <<= 1) {
        const int t = (tid >= off) ? tmp[tid - off] : 0;
        __syncthreads();
        tmp[tid] += t;
        __syncthreads();
    }
    const int incl = tmp[tid];
    if (idx < NROWS) sl_all[arr * NROWS + idx] = incl - val;
    if (tid == 255) bsum[arr * NBLK + blk] = incl;
}

// ---------------------------------------------------------------------------
// K2b: single-block scan of block sums -> block offsets (exclusive, per array).
// ---------------------------------------------------------------------------
__global__ __launch_bounds__(256) void scan_tops_kernel(
    const int* __restrict__ bsum,      // [3][NBLK]
    int* __restrict__ bo_all)          // [3][1024]
{
    __shared__ int tmp[256];
    __shared__ int s_carry;
    const int tid = threadIdx.x;
    for (int arr = 0; arr < 3; ++arr) {
        if (tid == 0) s_carry = 0;
        __syncthreads();
        for (int base = 0; base < NBLK; base += 256) {
            const int idx = base + tid;
            const int val = (idx < NBLK) ? bsum[arr * NBLK + idx] : 0;
            tmp[tid] = val;
            __syncthreads();
#pragma unroll
            for (int off = 1; off < 256; off <<= 1) {
                const int t = (tid >= off) ? tmp[tid - off] : 0;
                __syncthreads();
                tmp[tid] += t;
                __syncthreads();
            }
            const int incl = tmp[tid];
            if (idx < NBLK) bo_all[arr * 1024 + idx] = s_carry + (incl - val);
            __syncthreads();
            if (tid == 255) s_carry += tmp[255];
            __syncthreads();
        }
    }
}

// ---------------------------------------------------------------------------
// K3: scatter src ids into buckets (no atomics). Thread per edge.
// ---------------------------------------------------------------------------
__global__ __launch_bounds__(256) void scatter_kernel(
    const int* __restrict__ um, const int* __restrict__ me,
    const int* __restrict__ sl_all, const int* __restrict__ bo_all,
    const int* __restrict__ w_umu, const int* __restrict__ w_umm,
    const int* __restrict__ w_me,
    int* __restrict__ bk_u, int* __restrict__ bk_m, int* __restrict__ bk_e,
    int E_um, int E_me)
{
    const int* sl_u = sl_all;
    const int* sl_m = sl_all + NROWS;
    const int* sl_e = sl_all + 2 * NROWS;
    const int* bo_u = bo_all;
    const int* bo_m = bo_all + 1024;
    const int* bo_e = bo_all + 2048;
    const int total = E_um + E_me;
    for (int t = blockIdx.x * blockDim.x + threadIdx.x; t < total;
         t += gridDim.x * blockDim.x) {
        if (t < E_um) {
            const int a = um[t];
            const int b = um[E_um + t];
            bk_u[sl_u[a] + bo_u[a >> 8] + w_umu[t]] = b;   // user dst gathers user_x[b]
            bk_m[sl_m[b] + bo_m[b >> 8] + w_umm[t]] = a;   // movie dst gathers movie_x[a]
        } else {
            const int e = t - E_um;
            const int s = me[e];
            const int d = me[E_me + e];
            bk_e[sl_e[d] + bo_e[d >> 8] + w_me[e]] = s;    // movie dst gathers entity_x[s]
        }
    }
}

// ---------------------------------------------------------------------------
// K4: gather-accumulate. Wave per dst row (contiguous row ranges per wave),
// lane = channel. One plain 256B store per row, zero atomics.
// ---------------------------------------------------------------------------
__global__ __launch_bounds__(256) void gather_kernel(
    const int* __restrict__ bucket,
    const float* __restrict__ x,
    const int* __restrict__ cnt,
    const int* __restrict__ sl,
    const int* __restrict__ bo,
    float* __restrict__ outbase,   // row stride 128 floats
    int out_off, int nrows)
{
    const int lane = threadIdx.x & 63;
    const int wid = __builtin_amdgcn_readfirstlane(
        (blockIdx.x * blockDim.x + threadIdx.x) >> 6);
    const int nw = (gridDim.x * blockDim.x) >> 6;
    const int rpw = (nrows + nw - 1) / nw;
    const int r0 = wid * rpw;
    const int r1 = min(r0 + rpw, nrows);
    for (int r = r0; r < r1; ++r) {
        const int c = cnt[r];
        const int base = sl[r] + bo[r >> 8];
        float acc0 = 0.f, acc1 = 0.f;
        int j = 0;
        for (; j + 2 <= c; j += 2) {
            const int s0 = bucket[base + j];
            const int s1 = bucket[base + j + 1];
            acc0 += x[(size_t)s0 * 64 + lane];
            acc1 += x[(size_t)s1 * 64 + lane];
        }
        if (j < c) {
            const int s0 = bucket[base + j];
            acc0 += x[(size_t)s0 * 64 + lane];
        }
        outbase[(size_t)r * 128 + out_off + lane] = acc0 + acc1;
    }
}

// ---------------------------------------------------------------------------
// Finalize A (movies only): RGCN part.
// Reads S_e from out_movie[m][0..63], overwrites it with
//   r = (S_e@Wrel)/max(ce,1) + Ex@Wroot + brgcn
// ---------------------------------------------------------------------------
__global__ __launch_bounds__(256, 2) void finalize_rgcn_kernel(
    const float* __restrict__ entity_x,
    const int* __restrict__ cnt_e,
    const float* __restrict__ Wrel, const float* __restrict__ Wroot,
    const float* __restrict__ brgcn,
    float* __restrict__ out_movie)
{
    __shared__ float srow[4][128];
    __shared__ float brs[64];
    const int lane = threadIdx.x & 63;
    const int wslot = threadIdx.x >> 6;
    if (threadIdx.x < 64) brs[threadIdx.x] = brgcn[threadIdx.x];
    __syncthreads();

    float Wcr[64], Wco[64];
#pragma unroll
    for (int k = 0; k < 64; ++k) {
        Wcr[k] = Wrel[k * 64 + lane];
        Wco[k] = Wroot[k * 64 + lane];
    }
    const float bv = brs[lane];

    const int gw = (blockIdx.x * blockDim.x + threadIdx.x) >> 6;
    const int nw = (gridDim.x * blockDim.x) >> 6;

    int m = gw;
    if (m >= NMOVIES) return;

    float sev = out_movie[(size_t)m * 128 + lane];
    float exv = entity_x[(size_t)m * 64 + lane];
    float ce  = (float)cnt_e[m];

    while (m < NMOVIES) {
        srow[wslot][lane]      = sev;
        srow[wslot][64 + lane] = exv;

        const int mn = m + nw;
        float sevn = 0.f, exvn = 0.f, cen = 0.f;
        if (mn < NMOVIES) {
            sevn = out_movie[(size_t)mn * 128 + lane];
            exvn = entity_x[(size_t)mn * 64 + lane];
            cen  = (float)cnt_e[mn];
        }

        const float* sep = &srow[wslot][0];
        const float* exp_ = &srow[wslot][64];
        float a3a = 0.f, a3b = 0.f, a4a = 0.f, a4b = 0.f;
#pragma unroll
        for (int k = 0; k < 64; k += 4) {
            const float4 sv = *(const float4*)&sep[k];
            const float4 ev = *(const float4*)&exp_[k];
            a3a = fmaf(sv.x, Wcr[k],     a3a);
            a3b = fmaf(sv.y, Wcr[k + 1], a3b);
            a3a = fmaf(sv.z, Wcr[k + 2], a3a);
            a3b = fmaf(sv.w, Wcr[k + 3], a3b);
            a4a = fmaf(ev.x, Wco[k],     a4a);
            a4b = fmaf(ev.y, Wco[k + 1], a4b);
            a4a = fmaf(ev.z, Wco[k + 2], a4a);
            a4b = fmaf(ev.w, Wco[k + 3], a4b);
        }

        const float inv_ce = 1.0f / fmaxf(ce, 1.0f);
        out_movie[(size_t)m * 128 + lane] =
            (a3a + a3b) * inv_ce + a4a + a4b + bv;

        m = mn;
        sev = sevn; exv = exvn; ce = cen;
    }
}

// ---------------------------------------------------------------------------
// Finalize B (all 400k rows): NGCF transform + x-copy + rgcn add.
// out[r][64..127] = S1@W1 + (x ⊙ S1)@W2 + cnt*(b1+b2) + rgcn_part
// out[r][0..63]   = x[r]      (rgcn_part = 0 for users, in-register)
// ---------------------------------------------------------------------------
__global__ __launch_bounds__(256, 2) void finalize_ngcf_kernel(
    const float* __restrict__ user_x,
    const float* __restrict__ movie_x,
    const int* __restrict__ cntu,
    const int* __restrict__ cntm,
    const float* __restrict__ W1, const float* __restrict__ b1,
    const float* __restrict__ W2, const float* __restrict__ b2,
    float* __restrict__ out_user, float* __restrict__ out_movie)
{
    __shared__ float srow[4][128];
    __shared__ float biass[64];
    const int lane = threadIdx.x & 63;
    const int wslot = threadIdx.x >> 6;
    if (threadIdx.x < 64) biass[threadIdx.x] = b1[threadIdx.x] + b2[threadIdx.x];
    __syncthreads();

    float Wc1[64], Wc2[64];
#pragma unroll
    for (int k = 0; k < 64; ++k) {
        Wc1[k] = W1[k * 64 + lane];
        Wc2[k] = W2[k * 64 + lane];
    }
    const float bv = biass[lane];

    const int gw = (blockIdx.x * blockDim.x + threadIdx.x) >> 6;
    const int nw = (gridDim.x * blockDim.x) >> 6;

    int r = gw;
    if (r >= NROWSF1) return;

    float s1v, xv, cnt, rp;
    {
        const bool isU = r < NUSERS;
        const int row = isU ? r : r - NUSERS;
        float* outp = (isU ? out_user : out_movie) + (size_t)row * 128;
        s1v = outp[64 + lane];
        rp  = isU ? 0.f : outp[lane];
        xv  = ((isU ? user_x : movie_x) + (size_t)row * 64)[lane];
        cnt = (float)(isU ? cntu : cntm)[row];
    }

    while (r < NROWSF1) {
        srow[wslot][lane]      = s1v;
        srow[wslot][64 + lane] = xv;

        const int rn = r + nw;
        float s1n = 0.f, xvn = 0.f, cntn = 0.f, rpn = 0.f;
        if (rn < NROWSF1) {
            const bool isU = rn < NUSERS;
            const int row = isU ? rn : rn - NUSERS;
            float* outp = (isU ? out_user : out_movie) + (size_t)row * 128;
            s1n = outp[64 + lane];
            rpn = isU ? 0.f : outp[lane];
            xvn = ((isU ? user_x : movie_x) + (size_t)row * 64)[lane];
            cntn = (float)(isU ? cntu : cntm)[row];
        }

        const float* s1p = &srow[wslot][0];
        const float* xp  = &srow[wslot][64];
        float a1a = 0.f, a1b = 0.f, a2a = 0.f, a2b = 0.f;
#pragma unroll
        for (int k = 0; k < 64; k += 4) {
            const float4 s1q = *(const float4*)&s1p[k];
            const float4 xq  = *(const float4*)&xp[k];
            a1a = fmaf(s1q.x, Wc1[k],     a1a);
            a1b = fmaf(s1q.y, Wc1[k + 1], a1b);
            a1a = fmaf(s1q.z, Wc1[k + 2], a1a);
            a1b = fmaf(s1q.w, Wc1[k + 3], a1b);
            a2a = fmaf(xq.x * s1q.x, Wc2[k],     a2a);
            a2b = fmaf(xq.y * s1q.y, Wc2[k + 1], a2b);
            a2a = fmaf(xq.z * s1q.z, Wc2[k + 2], a2a);
            a2b = fmaf(xq.w * s1q.w, Wc2[k + 3], a2b);
        }

        {
            const bool isU = r < NUSERS;
            const int row = isU ? r : r - NUSERS;
            float* outp = (isU ? out_user : out_movie) + (size_t)row * 128;
            outp[lane] = xv;
            outp[64 + lane] = a1a + a1b + a2a + a2b + cnt * bv + rp;
        }
        r = rn;
        s1v = s1n; xv = xvn; cnt = cntn; rp = rpn;
    }
}

extern "C" void kernel_launch(void* const* d_in, const int* in_sizes, int n_in,
                              void* d_out, int out_size, void* d_ws, size_t ws_size,
                              hipStream_t stream)
{
    const float* user_x   = (const float*)d_in[0];
    const float* movie_x  = (const float*)d_in[1];
    const float* entity_x = (const float*)d_in[2];
    const int*   um       = (const int*)d_in[3];
    const int*   me       = (const int*)d_in[4];
    const float* W1       = (const float*)d_in[5];
    const float* b1       = (const float*)d_in[6];
    const float* W2       = (const float*)d_in[7];
    const float* b2       = (const float*)d_in[8];
    const float* Wrel     = (const float*)d_in[9];
    const float* Wroot    = (const float*)d_in[10];
    const float* brgcn    = (const float*)d_in[11];

    const int E_um = in_sizes[3] / 2;
    const int E_me = in_sizes[4] / 2;

    float* out_user  = (float*)d_out;                         // [NUSERS, 128]
    float* out_movie = out_user + (size_t)NUSERS * 128;       // [NMOVIES, 128]

    // Workspace layout (ints)
    int* cnt_all = (int*)d_ws;                 // [3][NROWS]  (u, m, e) - zeroed
    int* sl_all  = cnt_all + 3 * NROWS;        // [3][NROWS]
    int* bsum    = sl_all + 3 * NROWS;         // [3][NBLK]  (pad to 1024)
    int* bo_all  = bsum + 3 * 1024;            // [3][1024]
    int* w_umu   = bo_all + 3 * 1024;          // [E_um]
    int* w_umm   = w_umu + E_um;               // [E_um]
    int* w_me    = w_umm + E_um;               // [E_me]
    int* bk_u    = w_me + E_me;                // [E_um]
    int* bk_m    = bk_u + E_um;                // [E_um]
    int* bk_e    = bk_m + E_um;                // [E_me]

    int* cnt_u = cnt_all;
    int* cnt_m = cnt_all + NROWS;
    int* cnt_e = cnt_all + 2 * NROWS;

    // Only the histogram tables need zeroing (2.4 MB).
    hipMemsetAsync(cnt_all, 0, 3 * NROWS * sizeof(int), stream);

    hist_kernel<<<4096, 256, 0, stream>>>(um, me, cnt_u, cnt_m, cnt_e,
                                          w_umu, w_umm, w_me, E_um, E_me);
    scan_blocks_kernel<<<3 * NBLK, 256, 0, stream>>>(cnt_all, sl_all, bsum);
    scan_tops_kernel<<<1, 256, 0, stream>>>(bsum, bo_all);
    scatter_kernel<<<4096, 256, 0, stream>>>(um, me, sl_all, bo_all,
                                             w_umu, w_umm, w_me,
                                             bk_u, bk_m, bk_e, E_um, E_me);

    // Gather phases (stream-sequential so each side's x-table stays L3-hot).
    gather_kernel<<<2048, 256, 0, stream>>>(bk_e, entity_x, cnt_e,
                                            sl_all + 2 * NROWS, bo_all + 2048,
                                            out_movie, 0, NMOVIES);
    gather_kernel<<<2048, 256, 0, stream>>>(bk_m, movie_x, cnt_m,
                                            sl_all + NROWS, bo_all + 1024,
                                            out_movie, 64, NMOVIES);
    gather_kernel<<<2048, 256, 0, stream>>>(bk_u, user_x, cnt_u,
                                            sl_all, bo_all,
                                            out_user, 64, NUSERS);

    finalize_rgcn_kernel<<<2048, 256, 0, stream>>>(entity_x, cnt_e,
                                                   Wrel, Wroot, brgcn, out_movie);
    finalize_ngcf_kernel<<<4096, 256, 0, stream>>>(user_x, movie_x, cnt_u, cnt_m,
                                                   W1, b1, W2, b2,
                                                   out_user, out_movie);
}